// Round 7
// baseline (420.375 us; speedup 1.0000x reference)
//
#include <hip/hip_runtime.h>
#include <hip/hip_bf16.h>

#define CIN 384
#define PQ 1024
#define PKV 256
#define HEADS 6
#define DH 64
#define INNER 384
#define ATTN_SCALE 0.125f

typedef __hip_bfloat16 bf16;
typedef unsigned short ushort;
typedef __bf16 bf16x8 __attribute__((ext_vector_type(8)));
typedef float floatx4 __attribute__((ext_vector_type(4)));

__device__ __forceinline__ float b2f(bf16 v) { return __bfloat162float(v); }
__device__ __forceinline__ bf16 f2b(float v) { return __float2bfloat16(v); }
__device__ __forceinline__ ushort f2bu(float v) { bf16 h = __float2bfloat16(v); return *(ushort*)&h; }
__device__ __forceinline__ float ldf(const void* p, size_t i, int isbf) {
    return isbf ? __bfloat162float(((const bf16*)p)[i]) : ((const float*)p)[i];
}

// ---------------- input dtype probe ----------------------------------------------
__global__ void detect_kernel(const unsigned int* __restrict__ x, int* __restrict__ flag) {
    if (threadIdx.x == 0 && blockIdx.x == 0) {
        int cnt = 0;
        for (int i = 0; i < 64; i++) {
            unsigned int e = (x[i] >> 7) & 0xFFu;
            if (e >= 100u && e <= 140u) cnt++;
        }
        *flag = (cnt >= 48) ? 1 : 0;
    }
}

// ---------------- weight convert: 3 segments -> contiguous bf16 ------------------
__global__ void wconv_kernel(const void* __restrict__ w0, const void* __restrict__ w1,
                             const void* __restrict__ w2, bf16* __restrict__ dst,
                             const int* __restrict__ flagp) {
    int isbf = *flagp;
    const int n0 = INNER * CIN, n1 = 2 * INNER * CIN, n2 = INNER * CIN;
    int i = blockIdx.x * 256 + threadIdx.x;
    int total = n0 + n1 + n2;
    for (; i < total; i += gridDim.x * 256) {
        float v;
        if (i < n0) v = ldf(w0, i, isbf);
        else if (i < n0 + n1) v = ldf(w1, i - n0, isbf);
        else v = ldf(w2, i - n0 - n1, isbf);
        dst[i] = f2b(v);
    }
}

// ---------------- depthwise 3x3 + BN -> Y^T [b][p][c], coalesced writes ----------
template <int STRIDE, int HO, int WO>
__global__ __launch_bounds__(256) void dw_bn_kernel(
        const void* __restrict__ x, const void* __restrict__ wdw,
        const void* __restrict__ gamma, const void* __restrict__ beta,
        const void* __restrict__ mean, const void* __restrict__ var,
        bf16* __restrict__ yt, const int* __restrict__ flagp) {
    const int IN_ROWS = (8 - 1) * STRIDE + 3;
    __shared__ float xs[IN_ROWS][32][33];
    int isbf = *flagp;
    int rg = blockIdx.x;
    int c0 = blockIdx.y * 32;
    int b  = blockIdx.z;
    int tid = threadIdx.x;
    int ri0 = rg * 8 * STRIDE - 1;

    for (int idx = tid; idx < IN_ROWS * 32 * 32; idx += 256) {
        int w_ = idx & 31;
        int cc = (idx >> 5) & 31;
        int i  = idx >> 10;
        int row = ri0 + i;
        float v = 0.f;
        if (row >= 0 && row < 32)
            v = ldf(x, ((size_t)(b * CIN + c0 + cc) * 32 + row) * 32 + w_, isbf);
        xs[i][w_][cc] = v;
    }

    int cc = tid & 31;
    int g  = tid >> 5;
    int c  = c0 + cc;
    float w9[9];
#pragma unroll
    for (int k = 0; k < 9; k++) w9[k] = ldf(wdw, c * 9 + k, isbf);
    float inv = ldf(gamma, c, isbf) * rsqrtf(ldf(var, c, isbf) + 1e-5f);
    float bias = ldf(beta, c, isbf) - ldf(mean, c, isbf) * inv;
    __syncthreads();

    int orow = rg * 8 + g;
    bf16* orow_base = yt + ((size_t)b * (HO * WO) + (size_t)orow * WO) * CIN + c;
#pragma unroll
    for (int wo = 0; wo < WO; wo++) {
        float acc = 0.f;
#pragma unroll
        for (int ky = 0; ky < 3; ky++) {
#pragma unroll
            for (int kx = 0; kx < 3; kx++) {
                int ci = wo * STRIDE + kx - 1;
                if (ci < 0 || ci >= 32) continue;
                acc += w9[ky * 3 + kx] * xs[g * STRIDE + ky][ci][cc];
            }
        }
        orow_base[(size_t)wo * CIN] = f2b(acc * inv + bias);
    }
}

// ---------------- MFMA pointwise GEMM --------------------------------------------
template <int P, int MODE>
__global__ __launch_bounds__(256, 1) void mfma_pw(
        const bf16* __restrict__ wt, const bf16* __restrict__ yt,
        const void* __restrict__ bias, void* __restrict__ out0,
        bf16* __restrict__ out1, int O, const int* __restrict__ flagp) {
    int tid = threadIdx.x;
    int wave = tid >> 6, lane = tid & 63;
    int l15 = lane & 15, quad = lane >> 4;
    int wm = wave & 1, wn = wave >> 1;
    int b = blockIdx.z;
    int p0 = blockIdx.x * 128 + wm * 64;
    int o0 = blockIdx.y * 128 + wn * 64;

    const bf16* ybase = yt + (size_t)b * P * CIN;
    const bf16* arow[4];
    const bf16* brow[4];
#pragma unroll
    for (int pt = 0; pt < 4; pt++) arow[pt] = ybase + (size_t)(p0 + pt * 16 + l15) * CIN + quad * 8;
#pragma unroll
    for (int ot = 0; ot < 4; ot++) brow[ot] = wt + (size_t)(o0 + ot * 16 + l15) * CIN + quad * 8;

    floatx4 acc[4][4];
#pragma unroll
    for (int pt = 0; pt < 4; pt++)
#pragma unroll
        for (int ot = 0; ot < 4; ot++) acc[pt][ot] = (floatx4){0.f, 0.f, 0.f, 0.f};

#pragma unroll
    for (int k = 0; k < CIN; k += 32) {
        bf16x8 af[4], bw[4];
#pragma unroll
        for (int pt = 0; pt < 4; pt++) af[pt] = *(const bf16x8*)(arow[pt] + k);
#pragma unroll
        for (int ot = 0; ot < 4; ot++) bw[ot] = *(const bf16x8*)(brow[ot] + k);
#pragma unroll
        for (int pt = 0; pt < 4; pt++)
#pragma unroll
            for (int ot = 0; ot < 4; ot++)
                acc[pt][ot] = __builtin_amdgcn_mfma_f32_16x16x32_bf16(af[pt], bw[ot], acc[pt][ot], 0, 0, 0);
    }

    if (MODE == 2) {
        int isbf = *flagp;
#pragma unroll
        for (int ot = 0; ot < 4; ot++) {
            int o = o0 + ot * 16 + l15;
            float bv = ldf(bias, o, isbf);
#pragma unroll
            for (int pt = 0; pt < 4; pt++) {
                int p = p0 + pt * 16 + quad * 4;
                size_t idx = ((size_t)b * O + o) * P + p;
                if (!isbf) {
                    float4 v4 = {acc[pt][ot][0] + bv, acc[pt][ot][1] + bv,
                                 acc[pt][ot][2] + bv, acc[pt][ot][3] + bv};
                    *(float4*)((float*)out0 + idx) = v4;
                } else {
                    ushort4 u4 = {f2bu(acc[pt][ot][0] + bv), f2bu(acc[pt][ot][1] + bv),
                                  f2bu(acc[pt][ot][2] + bv), f2bu(acc[pt][ot][3] + bv)};
                    *(ushort4*)((bf16*)out0 + idx) = u4;
                }
            }
        }
    } else if (MODE == 0) {
#pragma unroll
        for (int ot = 0; ot < 4; ot++) {
            int o = o0 + ot * 16 + l15;
            int h = o >> 6, d = o & 63;
            bf16* base = (bf16*)out0 + ((size_t)(b * HEADS + h) * P) * 64 + d;
#pragma unroll
            for (int pt = 0; pt < 4; pt++)
#pragma unroll
                for (int r = 0; r < 4; r++)
                    base[(size_t)(p0 + pt * 16 + quad * 4 + r) * 64] = f2b(acc[pt][ot][r]);
        }
    } else {  // MODE 1: K | V fused
#pragma unroll
        for (int ot = 0; ot < 4; ot++) {
            int o = o0 + ot * 16 + l15;
            if (o < INNER) {
                int h = o >> 6, d = o & 63;
                bf16* base = (bf16*)out0 + ((size_t)(b * HEADS + h) * P) * 64 + d;
#pragma unroll
                for (int pt = 0; pt < 4; pt++)
#pragma unroll
                    for (int r = 0; r < 4; r++)
                        base[(size_t)(p0 + pt * 16 + quad * 4 + r) * 64] = f2b(acc[pt][ot][r]);
            } else {
                int ch = o - INNER;
                bf16* base = out1 + ((size_t)b * INNER + ch) * P;
#pragma unroll
                for (int pt = 0; pt < 4; pt++)
#pragma unroll
                    for (int r = 0; r < 4; r++)
                        base[p0 + pt * 16 + quad * 4 + r] = f2b(acc[pt][ot][r]);
            }
        }
    }
}

// ---------------- fused MFMA attention -------------------------------------------
// Pipelined frag loads (double-buffered register groups) + XCD-locality swizzle.
// out layout: ao[b][p][h*64+d]
__global__ __launch_bounds__(256, 1) void attn_kernel(
        const bf16* __restrict__ qalt, const bf16* __restrict__ kalt,
        const bf16* __restrict__ valt, bf16* __restrict__ ao) {
    __shared__ __align__(16) ushort Pl[4][16][264];
    __shared__ __align__(16) ushort Ot[4][16][80];
    int tid = threadIdx.x;
    int wave = tid >> 6, lane = tid & 63;
    int l15 = lane & 15, quad = lane >> 4;
    int blk = blockIdx.x;
    // XCD swizzle: all 16 tiles of one (b,h) have blk ≡ hg (mod 192); 192%8==0 ->
    // same XCD under round-robin dispatch -> that head's K/V stays in one L2.
    int hg = blk % (32 * HEADS);
    int tile = blk / (32 * HEADS);
    int b = hg / HEADS;
    int h = hg % HEADS;
    int p0 = tile * 64 + wave * 16;

    const bf16* qbase = qalt + (size_t)(b * HEADS + h) * PQ * DH;
    const bf16* kbase = kalt + (size_t)(b * HEADS + h) * PKV * DH;
    const bf16* vbase = valt + ((size_t)b * INNER + h * DH) * PKV;

    const bf16* qrow = qbase + (size_t)(p0 + l15) * DH + quad * 8;
    bf16x8 a0 = *(const bf16x8*)qrow;
    bf16x8 a1 = *(const bf16x8*)(qrow + 32);

    const bf16* krow0 = kbase + (size_t)l15 * DH + quad * 8;

    floatx4 s[16];
#pragma unroll
    for (int jt = 0; jt < 16; jt++) s[jt] = (floatx4){0.f, 0.f, 0.f, 0.f};

    // S = Q K^T, K-frags in double-buffered groups of 4 j-tiles (8 loads in flight)
    bf16x8 kf[2][2][4];
#pragma unroll
    for (int u = 0; u < 4; u++) {
        kf[0][0][u] = *(const bf16x8*)(krow0 + (size_t)u * 16 * DH);
        kf[0][1][u] = *(const bf16x8*)(krow0 + (size_t)u * 16 * DH + 32);
    }
#pragma unroll
    for (int g = 0; g < 4; g++) {
        const int cb = g & 1, nb = (g & 1) ^ 1;
        if (g < 3) {
#pragma unroll
            for (int u = 0; u < 4; u++) {
                kf[nb][0][u] = *(const bf16x8*)(krow0 + (size_t)((g + 1) * 4 + u) * 16 * DH);
                kf[nb][1][u] = *(const bf16x8*)(krow0 + (size_t)((g + 1) * 4 + u) * 16 * DH + 32);
            }
        }
#pragma unroll
        for (int u = 0; u < 4; u++) {
            s[g * 4 + u] = __builtin_amdgcn_mfma_f32_16x16x32_bf16(a0, kf[cb][0][u], s[g * 4 + u], 0, 0, 0);
            s[g * 4 + u] = __builtin_amdgcn_mfma_f32_16x16x32_bf16(a1, kf[cb][1][u], s[g * 4 + u], 0, 0, 0);
        }
    }

#pragma unroll
    for (int r = 0; r < 4; r++) {
        float mx = s[0][r];
#pragma unroll
        for (int jt = 1; jt < 16; jt++) mx = fmaxf(mx, s[jt][r]);
#pragma unroll
        for (int off = 1; off <= 8; off <<= 1) mx = fmaxf(mx, __shfl_xor(mx, off, 64));
        float sm = 0.f;
#pragma unroll
        for (int jt = 0; jt < 16; jt++) {
            float e = __expf((s[jt][r] - mx) * ATTN_SCALE);
            s[jt][r] = e;
            sm += e;
        }
#pragma unroll
        for (int off = 1; off <= 8; off <<= 1) sm += __shfl_xor(sm, off, 64);
        float inv = 1.f / sm;
#pragma unroll
        for (int jt = 0; jt < 16; jt++)
            Pl[wave][quad * 4 + r][jt * 16 + l15] = f2bu(s[jt][r] * inv);
    }
    __syncthreads();

    // O = P V, V-frags in double-buffered groups of 8 (one n-tile ahead)
    floatx4 oacc[4];
#pragma unroll
    for (int nt = 0; nt < 4; nt++) oacc[nt] = (floatx4){0.f, 0.f, 0.f, 0.f};
    bf16x8 pa[8];
#pragma unroll
    for (int kk = 0; kk < 8; kk++)
        pa[kk] = *(const bf16x8*)&Pl[wave][l15][kk * 32 + quad * 8];

    const bf16* vrow0 = vbase + (size_t)l15 * PKV + quad * 8;
    bf16x8 vf[2][8];
#pragma unroll
    for (int kk = 0; kk < 8; kk++)
        vf[0][kk] = *(const bf16x8*)(vrow0 + kk * 32);
#pragma unroll
    for (int nt = 0; nt < 4; nt++) {
        const int cb = nt & 1, nb = (nt & 1) ^ 1;
        if (nt < 3) {
#pragma unroll
            for (int kk = 0; kk < 8; kk++)
                vf[nb][kk] = *(const bf16x8*)(vrow0 + (size_t)(nt + 1) * 16 * PKV + kk * 32);
        }
#pragma unroll
        for (int kk = 0; kk < 8; kk++)
            oacc[nt] = __builtin_amdgcn_mfma_f32_16x16x32_bf16(pa[kk], vf[cb][kk], oacc[nt], 0, 0, 0);
    }

    // C-layout -> LDS -> coalesced [p][c] store
#pragma unroll
    for (int nt = 0; nt < 4; nt++)
#pragma unroll
        for (int r = 0; r < 4; r++)
            Ot[wave][quad * 4 + r][nt * 16 + l15] = f2bu(oacc[nt][r]);
    int row = lane >> 2, d0 = (lane & 3) * 16;
    uint4 ld0 = *(const uint4*)&Ot[wave][row][d0];
    uint4 ld1 = *(const uint4*)&Ot[wave][row][d0 + 8];
    bf16* dst = ao + ((size_t)b * PQ + p0 + row) * INNER + h * DH + d0;
    *(uint4*)dst = ld0;
    *(uint4*)(dst + 8) = ld1;
}

extern "C" void kernel_launch(void* const* d_in, const int* in_sizes, int n_in,
                              void* d_out, int out_size, void* d_ws, size_t ws_size,
                              hipStream_t stream) {
    const void* x        = d_in[0];
    const void* q_dw     = d_in[1];
    const void* q_gamma  = d_in[2];
    const void* q_beta   = d_in[3];
    const void* q_mean   = d_in[4];
    const void* q_var    = d_in[5];
    const void* q_pw     = d_in[6];
    const void* kv_dw    = d_in[7];
    const void* kv_gamma = d_in[8];
    const void* kv_beta  = d_in[9];
    const void* kv_mean  = d_in[10];
    const void* kv_var   = d_in[11];
    const void* kv_pw    = d_in[12];
    const void* out_w    = d_in[13];
    const void* out_b    = d_in[14];

    int* flag = (int*)d_ws;
    bf16* pool = (bf16*)((char*)d_ws + 256);
    bf16* yqt  = pool;                              // [32,1024,384] Y^T Q-path; reused as aob
    bf16* ykvt = yqt  + (size_t)32 * 1024 * 384;    // [32,256,384]  Y^T KV-path
    bf16* qalt = ykvt + (size_t)32 * 256 * 384;     // [32,6,1024,64]
    bf16* kalt = qalt + (size_t)32 * 6 * 1024 * 64; // [32,6,256,64]
    bf16* valt = kalt + (size_t)32 * 6 * 256 * 64;  // [32,384,256]
    bf16* wbf  = valt + (size_t)32 * 384 * 256;     // q_pw | kv_pw | out_w bf16
    bf16* qpw_bf = wbf;
    bf16* kvpw_bf = wbf + (size_t)INNER * CIN;
    bf16* outw_bf = kvpw_bf + (size_t)2 * INNER * CIN;
    bf16* aob  = yqt;  // alias: yqt dead after Q pointwise; attn writes [b][p][c]

    detect_kernel<<<1, 64, 0, stream>>>((const unsigned int*)x, flag);
    wconv_kernel<<<576, 256, 0, stream>>>(q_pw, kv_pw, out_w, wbf, flag);
    dw_bn_kernel<1, 32, 32><<<dim3(4, 12, 32), 256, 0, stream>>>(x, q_dw, q_gamma, q_beta, q_mean, q_var, yqt, flag);
    dw_bn_kernel<2, 16, 16><<<dim3(2, 12, 32), 256, 0, stream>>>(x, kv_dw, kv_gamma, kv_beta, kv_mean, kv_var, ykvt, flag);
    mfma_pw<1024, 0><<<dim3(8, 3, 32), 256, 0, stream>>>(qpw_bf, yqt, nullptr, qalt, nullptr, INNER, flag);
    mfma_pw<256, 1><<<dim3(2, 6, 32), 256, 0, stream>>>(kvpw_bf, ykvt, nullptr, kalt, valt, 2 * INNER, flag);
    attn_kernel<<<32 * 6 * 16, 256, 0, stream>>>(qalt, kalt, valt, aob);
    mfma_pw<1024, 2><<<dim3(8, 3, 32), 256, 0, stream>>>(outw_bf, aob, out_b, d_out, nullptr, CIN, flag);
}

// Round 8
// 313.912 us; speedup vs baseline: 1.3391x; 1.3391x over previous
//
#include <hip/hip_runtime.h>
#include <hip/hip_bf16.h>

#define CIN 384
#define PQ 1024
#define PKV 256
#define HEADS 6
#define DH 64
#define INNER 384
#define ATTN_SCALE 0.125f

typedef __hip_bfloat16 bf16;
typedef unsigned short ushort;
typedef __bf16 bf16x8 __attribute__((ext_vector_type(8)));
typedef float floatx4 __attribute__((ext_vector_type(4)));

__device__ __forceinline__ float b2f(bf16 v) { return __bfloat162float(v); }
__device__ __forceinline__ bf16 f2b(float v) { return __float2bfloat16(v); }
__device__ __forceinline__ ushort f2bu(float v) { bf16 h = __float2bfloat16(v); return *(ushort*)&h; }
__device__ __forceinline__ float ldf(const void* p, size_t i, int isbf) {
    return isbf ? __bfloat162float(((const bf16*)p)[i]) : ((const float*)p)[i];
}
// async global->LDS DMA, 16B per lane; LDS dest = uniform base + lane*16
__device__ __forceinline__ void dma16(const bf16* g, bf16* l) {
    __builtin_amdgcn_global_load_lds(
        (const __attribute__((address_space(1))) unsigned int*)g,
        (__attribute__((address_space(3))) unsigned int*)l, 16, 0, 0);
}

// ---------------- input dtype probe ----------------------------------------------
__global__ void detect_kernel(const unsigned int* __restrict__ x, int* __restrict__ flag) {
    if (threadIdx.x == 0 && blockIdx.x == 0) {
        int cnt = 0;
        for (int i = 0; i < 64; i++) {
            unsigned int e = (x[i] >> 7) & 0xFFu;
            if (e >= 100u && e <= 140u) cnt++;
        }
        *flag = (cnt >= 48) ? 1 : 0;
    }
}

// ---------------- weight convert: 3 segments -> contiguous bf16 ------------------
__global__ void wconv_kernel(const void* __restrict__ w0, const void* __restrict__ w1,
                             const void* __restrict__ w2, bf16* __restrict__ dst,
                             const int* __restrict__ flagp) {
    int isbf = *flagp;
    const int n0 = INNER * CIN, n1 = 2 * INNER * CIN, n2 = INNER * CIN;
    int i = blockIdx.x * 256 + threadIdx.x;
    int total = n0 + n1 + n2;
    for (; i < total; i += gridDim.x * 256) {
        float v;
        if (i < n0) v = ldf(w0, i, isbf);
        else if (i < n0 + n1) v = ldf(w1, i - n0, isbf);
        else v = ldf(w2, i - n0 - n1, isbf);
        dst[i] = f2b(v);
    }
}

// ---------------- depthwise 3x3 + BN -> Y^T [b][p][c], coalesced writes ----------
template <int STRIDE, int HO, int WO>
__global__ __launch_bounds__(256) void dw_bn_kernel(
        const void* __restrict__ x, const void* __restrict__ wdw,
        const void* __restrict__ gamma, const void* __restrict__ beta,
        const void* __restrict__ mean, const void* __restrict__ var,
        bf16* __restrict__ yt, const int* __restrict__ flagp) {
    const int IN_ROWS = (8 - 1) * STRIDE + 3;
    __shared__ float xs[IN_ROWS][32][33];
    int isbf = *flagp;
    int rg = blockIdx.x;
    int c0 = blockIdx.y * 32;
    int b  = blockIdx.z;
    int tid = threadIdx.x;
    int ri0 = rg * 8 * STRIDE - 1;

    for (int idx = tid; idx < IN_ROWS * 32 * 32; idx += 256) {
        int w_ = idx & 31;
        int cc = (idx >> 5) & 31;
        int i  = idx >> 10;
        int row = ri0 + i;
        float v = 0.f;
        if (row >= 0 && row < 32)
            v = ldf(x, ((size_t)(b * CIN + c0 + cc) * 32 + row) * 32 + w_, isbf);
        xs[i][w_][cc] = v;
    }

    int cc = tid & 31;
    int g  = tid >> 5;
    int c  = c0 + cc;
    float w9[9];
#pragma unroll
    for (int k = 0; k < 9; k++) w9[k] = ldf(wdw, c * 9 + k, isbf);
    float inv = ldf(gamma, c, isbf) * rsqrtf(ldf(var, c, isbf) + 1e-5f);
    float bias = ldf(beta, c, isbf) - ldf(mean, c, isbf) * inv;
    __syncthreads();

    int orow = rg * 8 + g;
    bf16* orow_base = yt + ((size_t)b * (HO * WO) + (size_t)orow * WO) * CIN + c;
#pragma unroll
    for (int wo = 0; wo < WO; wo++) {
        float acc = 0.f;
#pragma unroll
        for (int ky = 0; ky < 3; ky++) {
#pragma unroll
            for (int kx = 0; kx < 3; kx++) {
                int ci = wo * STRIDE + kx - 1;
                if (ci < 0 || ci >= 32) continue;
                acc += w9[ky * 3 + kx] * xs[g * STRIDE + ky][ci][cc];
            }
        }
        orow_base[(size_t)wo * CIN] = f2b(acc * inv + bias);
    }
}

// ---------------- MFMA pointwise GEMM, m97-style LDS-staged, double-buffered -----
// C^T[p][o] = sum_c Yt[b][p][c] * W[o][c]. 128x128 tile, BK=32.
// LDS rows 64B (4x16B chunks), chunk slot = c ^ (row&3) -> <=4-way on ds_read_b128.
template <int P, int MODE>
__global__ __launch_bounds__(256, 2) void mfma_pw(
        const bf16* __restrict__ wt, const bf16* __restrict__ yt,
        const void* __restrict__ bias, void* __restrict__ out0,
        bf16* __restrict__ out1, int O, const int* __restrict__ flagp) {
    __shared__ __align__(16) bf16 As[2][4096];  // 128 rows x 32 k
    __shared__ __align__(16) bf16 Bs[2][4096];
    int tid = threadIdx.x;
    int wave = tid >> 6, lane = tid & 63;
    int l15 = lane & 15, quad = lane >> 4;
    int wm = wave & 1, wn = wave >> 1;
    int b = blockIdx.z;
    int p0 = blockIdx.x * 128;
    int o0 = blockIdx.y * 128;

    const bf16* asrc = yt + ((size_t)b * P + p0) * CIN;
    const bf16* bsrc = wt + (size_t)o0 * CIN;

    // DMA staging: per wave 2 issues A + 2 issues B (16 rows x 32k each)
    int srow = (lane >> 2);           // 0..15 within issue
    int sc   = lane & 3;              // chunk slot
    auto stage = [&](int step, int buf) {
#pragma unroll
        for (int it = 0; it < 2; it++) {
            int row = wave * 32 + it * 16 + srow;
            int g = sc ^ (row & 3);
            size_t goff = (size_t)row * CIN + step * 32 + g * 8;
            dma16(asrc + goff, &As[buf][(wave * 2 + it) * 512]);
            dma16(bsrc + goff, &Bs[buf][(wave * 2 + it) * 512]);
        }
    };

    floatx4 acc[4][4];
#pragma unroll
    for (int pt = 0; pt < 4; pt++)
#pragma unroll
        for (int ot = 0; ot < 4; ot++) acc[pt][ot] = (floatx4){0.f, 0.f, 0.f, 0.f};

    stage(0, 0);
    __syncthreads();
    for (int s = 0; s < CIN / 32; s++) {
        int buf = s & 1;
        if (s < CIN / 32 - 1) stage(s + 1, buf ^ 1);
        bf16x8 af[4], bw[4];
        int slot = (quad ^ (l15 & 3)) * 8;
#pragma unroll
        for (int pt = 0; pt < 4; pt++)
            af[pt] = *(const bf16x8*)&As[buf][(wm * 64 + pt * 16 + l15) * 32 + slot];
#pragma unroll
        for (int ot = 0; ot < 4; ot++)
            bw[ot] = *(const bf16x8*)&Bs[buf][(wn * 64 + ot * 16 + l15) * 32 + slot];
#pragma unroll
        for (int pt = 0; pt < 4; pt++)
#pragma unroll
            for (int ot = 0; ot < 4; ot++)
                acc[pt][ot] = __builtin_amdgcn_mfma_f32_16x16x32_bf16(af[pt], bw[ot], acc[pt][ot], 0, 0, 0);
        __syncthreads();
    }

    int pw0 = p0 + wm * 64, ow0 = o0 + wn * 64;
    if (MODE == 2) {
        int isbf = *flagp;
#pragma unroll
        for (int ot = 0; ot < 4; ot++) {
            int o = ow0 + ot * 16 + l15;
            float bv = ldf(bias, o, isbf);
#pragma unroll
            for (int pt = 0; pt < 4; pt++) {
                int p = pw0 + pt * 16 + quad * 4;
                size_t idx = ((size_t)b * O + o) * P + p;
                if (!isbf) {
                    float4 v4 = {acc[pt][ot][0] + bv, acc[pt][ot][1] + bv,
                                 acc[pt][ot][2] + bv, acc[pt][ot][3] + bv};
                    *(float4*)((float*)out0 + idx) = v4;
                } else {
                    ushort4 u4 = {f2bu(acc[pt][ot][0] + bv), f2bu(acc[pt][ot][1] + bv),
                                  f2bu(acc[pt][ot][2] + bv), f2bu(acc[pt][ot][3] + bv)};
                    *(ushort4*)((bf16*)out0 + idx) = u4;
                }
            }
        }
    } else if (MODE == 0) {
#pragma unroll
        for (int ot = 0; ot < 4; ot++) {
            int o = ow0 + ot * 16 + l15;
            int h = o >> 6, d = o & 63;
            bf16* base = (bf16*)out0 + ((size_t)(b * HEADS + h) * P) * 64 + d;
#pragma unroll
            for (int pt = 0; pt < 4; pt++)
#pragma unroll
                for (int r = 0; r < 4; r++)
                    base[(size_t)(pw0 + pt * 16 + quad * 4 + r) * 64] = f2b(acc[pt][ot][r]);
        }
    } else {  // MODE 1: K | V fused
#pragma unroll
        for (int ot = 0; ot < 4; ot++) {
            int o = ow0 + ot * 16 + l15;
            if (o < INNER) {
                int h = o >> 6, d = o & 63;
                bf16* base = (bf16*)out0 + ((size_t)(b * HEADS + h) * P) * 64 + d;
#pragma unroll
                for (int pt = 0; pt < 4; pt++)
#pragma unroll
                    for (int r = 0; r < 4; r++)
                        base[(size_t)(pw0 + pt * 16 + quad * 4 + r) * 64] = f2b(acc[pt][ot][r]);
            } else {
                int ch = o - INNER;
                bf16* base = out1 + ((size_t)b * INNER + ch) * PKV;
#pragma unroll
                for (int pt = 0; pt < 4; pt++)
#pragma unroll
                    for (int r = 0; r < 4; r++)
                        base[pw0 + pt * 16 + quad * 4 + r] = f2b(acc[pt][ot][r]);
            }
        }
    }
}

// ---------------- fused MFMA attention, LDS-staged K/V via DMA -------------------
// K staged swizzled (rows 128B, slot = c^(j&7)); V staged swizzled (rows 512B,
// slot = c^(d&15)); P aliases K region after barrier. out: ao[b][p][h*64+d]
__global__ __launch_bounds__(256, 2) void attn_kernel(
        const bf16* __restrict__ qalt, const bf16* __restrict__ kalt,
        const bf16* __restrict__ valt, bf16* __restrict__ ao) {
    __shared__ __align__(16) bf16 Kl[16384];        // 32 KB; becomes P after barrier 2
    __shared__ __align__(16) bf16 Vl[16384];        // 32 KB
    __shared__ __align__(16) ushort Ot[4][16][80];  // 10 KB
    int tid = threadIdx.x;
    int wave = tid >> 6, lane = tid & 63;
    int l15 = lane & 15, quad = lane >> 4;
    int blk = blockIdx.x;
    int hg = blk % (32 * HEADS);
    int tile = blk / (32 * HEADS);
    int b = hg / HEADS;
    int h = hg % HEADS;
    int p0 = tile * 64 + wave * 16;

    const bf16* qbase = qalt + (size_t)(b * HEADS + h) * PQ * DH;
    const bf16* kbase = kalt + (size_t)(b * HEADS + h) * PKV * DH;
    const bf16* vbase = valt + ((size_t)b * INNER + h * DH) * PKV;

    // Q frags (direct per-lane loads)
    const bf16* qrow = qbase + (size_t)(p0 + l15) * DH + quad * 8;
    bf16x8 a0 = *(const bf16x8*)qrow;
    bf16x8 a1 = *(const bf16x8*)(qrow + 32);

    // stage K: 32 issues (8/wave), 8 rows of 64 elems each
    {
        int j = (lane >> 3);       // row within issue group
        int cs = lane & 7;
#pragma unroll
        for (int it = 0; it < 8; it++) {
            int jb = (wave * 8 + it) * 8;
            int jr = jb + j;
            int g = cs ^ (jr & 7);
            dma16(kbase + (size_t)jr * 64 + g * 8, &Kl[(size_t)(wave * 8 + it) * 512]);
        }
        // stage V: 32 issues (8/wave), 2 rows of 256 elems each
        int d = (lane >> 5);
        int cs2 = lane & 31;
#pragma unroll
        for (int it = 0; it < 8; it++) {
            int db = (wave * 8 + it) * 2;
            int dr = db + d;
            int g = cs2 ^ (dr & 15);
            dma16(vbase + (size_t)dr * 256 + g * 8, &Vl[(size_t)(wave * 8 + it) * 512]);
        }
    }
    __syncthreads();  // drains DMA (vmcnt) + cross-wave staging visibility

    // S = Q K^T from LDS
    floatx4 s[16];
#pragma unroll
    for (int jt = 0; jt < 16; jt++) s[jt] = (floatx4){0.f, 0.f, 0.f, 0.f};
#pragma unroll
    for (int jt = 0; jt < 16; jt++) {
        int j = jt * 16 + l15;
        bf16x8 b0 = *(const bf16x8*)&Kl[j * 64 + (quad ^ (j & 7)) * 8];
        bf16x8 b1 = *(const bf16x8*)&Kl[j * 64 + ((4 + quad) ^ (j & 7)) * 8];
        s[jt] = __builtin_amdgcn_mfma_f32_16x16x32_bf16(a0, b0, s[jt], 0, 0, 0);
        s[jt] = __builtin_amdgcn_mfma_f32_16x16x32_bf16(a1, b1, s[jt], 0, 0, 0);
    }

    // softmax (in registers)
    float pinv[4];
#pragma unroll
    for (int r = 0; r < 4; r++) {
        float mx = s[0][r];
#pragma unroll
        for (int jt = 1; jt < 16; jt++) mx = fmaxf(mx, s[jt][r]);
#pragma unroll
        for (int off = 1; off <= 8; off <<= 1) mx = fmaxf(mx, __shfl_xor(mx, off, 64));
        float sm = 0.f;
#pragma unroll
        for (int jt = 0; jt < 16; jt++) {
            float e = __expf((s[jt][r] - mx) * ATTN_SCALE);
            s[jt][r] = e;
            sm += e;
        }
#pragma unroll
        for (int off = 1; off <= 8; off <<= 1) sm += __shfl_xor(sm, off, 64);
        pinv[r] = 1.f / sm;
    }
    __syncthreads();  // all waves done reading Kl -> safe to overwrite with P

    // P (bf16) into Kl region, swizzled rows 512B: slot = c ^ row
    ushort* Plw = (ushort*)&Kl[wave * 4096];
#pragma unroll
    for (int r = 0; r < 4; r++) {
        int row = quad * 4 + r;
#pragma unroll
        for (int jt = 0; jt < 16; jt++) {
            int c = jt * 2 + (l15 >> 3);
            Plw[row * 256 + (c ^ row) * 8 + (l15 & 7)] = f2bu(s[jt][r] * pinv[r]);
        }
    }
    // P A-frags (wave-local; lgkmcnt orders write->read)
    bf16x8 pa[8];
#pragma unroll
    for (int kk = 0; kk < 8; kk++)
        pa[kk] = *(const bf16x8*)&Plw[l15 * 256 + ((kk * 4 + quad) ^ l15) * 8];

    // O = P V from LDS
    floatx4 oacc[4];
#pragma unroll
    for (int nt = 0; nt < 4; nt++) oacc[nt] = (floatx4){0.f, 0.f, 0.f, 0.f};
#pragma unroll
    for (int nt = 0; nt < 4; nt++) {
        int d = nt * 16 + l15;
#pragma unroll
        for (int kk = 0; kk < 8; kk++) {
            bf16x8 bv = *(const bf16x8*)&Vl[d * 256 + ((kk * 4 + quad) ^ l15) * 8];
            oacc[nt] = __builtin_amdgcn_mfma_f32_16x16x32_bf16(pa[kk], bv, oacc[nt], 0, 0, 0);
        }
    }

    // C-layout -> LDS -> coalesced [p][c] store
#pragma unroll
    for (int nt = 0; nt < 4; nt++)
#pragma unroll
        for (int r = 0; r < 4; r++)
            Ot[wave][quad * 4 + r][nt * 16 + l15] = f2bu(oacc[nt][r]);
    int row = lane >> 2, d0 = (lane & 3) * 16;
    uint4 ld0 = *(const uint4*)&Ot[wave][row][d0];
    uint4 ld1 = *(const uint4*)&Ot[wave][row][d0 + 8];
    bf16* dst = ao + ((size_t)b * PQ + p0 + row) * INNER + h * DH + d0;
    *(uint4*)dst = ld0;
    *(uint4*)(dst + 8) = ld1;
}

extern "C" void kernel_launch(void* const* d_in, const int* in_sizes, int n_in,
                              void* d_out, int out_size, void* d_ws, size_t ws_size,
                              hipStream_t stream) {
    const void* x        = d_in[0];
    const void* q_dw     = d_in[1];
    const void* q_gamma  = d_in[2];
    const void* q_beta   = d_in[3];
    const void* q_mean   = d_in[4];
    const void* q_var    = d_in[5];
    const void* q_pw     = d_in[6];
    const void* kv_dw    = d_in[7];
    const void* kv_gamma = d_in[8];
    const void* kv_beta  = d_in[9];
    const void* kv_mean  = d_in[10];
    const void* kv_var   = d_in[11];
    const void* kv_pw    = d_in[12];
    const void* out_w    = d_in[13];
    const void* out_b    = d_in[14];

    int* flag = (int*)d_ws;
    bf16* pool = (bf16*)((char*)d_ws + 256);
    bf16* yqt  = pool;                              // [32,1024,384] Y^T Q-path; reused as aob
    bf16* ykvt = yqt  + (size_t)32 * 1024 * 384;    // [32,256,384]  Y^T KV-path
    bf16* qalt = ykvt + (size_t)32 * 256 * 384;     // [32,6,1024,64]
    bf16* kalt = qalt + (size_t)32 * 6 * 1024 * 64; // [32,6,256,64]
    bf16* valt = kalt + (size_t)32 * 6 * 256 * 64;  // [32,384,256]
    bf16* wbf  = valt + (size_t)32 * 384 * 256;     // q_pw | kv_pw | out_w bf16
    bf16* qpw_bf = wbf;
    bf16* kvpw_bf = wbf + (size_t)INNER * CIN;
    bf16* outw_bf = kvpw_bf + (size_t)2 * INNER * CIN;
    bf16* aob  = yqt;  // alias: yqt dead after Q pointwise; attn writes [b][p][c]

    detect_kernel<<<1, 64, 0, stream>>>((const unsigned int*)x, flag);
    wconv_kernel<<<576, 256, 0, stream>>>(q_pw, kv_pw, out_w, wbf, flag);
    dw_bn_kernel<1, 32, 32><<<dim3(4, 12, 32), 256, 0, stream>>>(x, q_dw, q_gamma, q_beta, q_mean, q_var, yqt, flag);
    dw_bn_kernel<2, 16, 16><<<dim3(2, 12, 32), 256, 0, stream>>>(x, kv_dw, kv_gamma, kv_beta, kv_mean, kv_var, ykvt, flag);
    mfma_pw<1024, 0><<<dim3(8, 3, 32), 256, 0, stream>>>(qpw_bf, yqt, nullptr, qalt, nullptr, INNER, flag);
    mfma_pw<256, 1><<<dim3(2, 6, 32), 256, 0, stream>>>(kvpw_bf, ykvt, nullptr, kalt, valt, 2 * INNER, flag);
    attn_kernel<<<32 * 6 * 16, 256, 0, stream>>>(qalt, kalt, valt, aob);
    mfma_pw<1024, 2><<<dim3(8, 3, 32), 256, 0, stream>>>(outw_bf, aob, out_b, d_out, nullptr, CIN, flag);
}